// Round 4
// baseline (798.056 us; speedup 1.0000x reference)
//
#include <hip/hip_runtime.h>
#include <hip/hip_bf16.h>

#define CB 64      // B == C == 64
#define HH 128
#define WW 128
#define KK 4
#define EPSV 1e-5f
#define HWSZ (HH*WW)

using f32x4  = __attribute__((ext_vector_type(4))) float;
using short8 = __attribute__((ext_vector_type(8))) short;

// ---- workspace layout ----
// float element offsets (small area, < 4 MiB):
static constexpr size_t WS_POOLED = 0;          // [64][128]
static constexpr size_t WS_HID    = 8192;       // [64][64]
static constexpr size_t WS_KERN   = 12288;      // [64][2304] (dead after k_wk; bf16 weights reuse bytes)
static constexpr size_t WS_SSQ    = 159744;     // [64][4]
static constexpr size_t WS_WK     = 160000;     // [64][576]
static constexpr size_t WS_EFFW   = 196864;     // [64][576]
static constexpr size_t WS_FUW2   = 233728;     // [64][64]
static constexpr size_t WS_FDINV  = 237824;     // [64]
static constexpr size_t WS_FDBETA = 237888;     // [64]
static constexpr size_t WS_FUINV  = 237952;     // [64]
static constexpr size_t WS_FUBETA = 238016;     // [64]
// byte offsets inside dead WS_KERN byte range (49152..638976):
static constexpr size_t WT3_BYTE = 49152;              // bf16 [9][64][64]
static constexpr size_t WFD_BYTE = 49152 + 73728;      // bf16 [9][64][64]
static constexpr size_t W1_BYTE  = 49152 + 147456;     // bf16 [64][64]
// big buffers:
static constexpr size_t WS_PART_BYTE   = 4u << 20;     // f32 [64][128][128] partial row sums
static constexpr size_t WS_DEPTHT_BYTE = 8u << 20;     // bf16 [64][130][130][64] zero-padded (132 MB)
static constexpr size_t WS_RGBT_BYTE   = 140u << 20;   // bf16 [64][130][130][64] zero-padded

// ---------------- small kernels (verified rounds 1-3) ----------------

__global__ void k_consts(const float* __restrict__ fd_scale, const float* __restrict__ fd_bias,
                         const float* __restrict__ fd_mean, const float* __restrict__ fd_var,
                         const float* __restrict__ fd_b,
                         const float* __restrict__ fu_scale, const float* __restrict__ fu_bias,
                         const float* __restrict__ fu_mean, const float* __restrict__ fu_var,
                         const float* __restrict__ fu_b,
                         float* __restrict__ ws) {
    int c = threadIdx.x;
    if (c < CB) {
        float fdi = fd_scale[c] / sqrtf(fd_var[c] + EPSV);
        ws[WS_FDINV + c]  = fdi;
        ws[WS_FDBETA + c] = (fd_b[c] - fd_mean[c]) * fdi + fd_bias[c];
        float fui = fu_scale[c] / sqrtf(fu_var[c] + EPSV);
        ws[WS_FUINV + c]  = fui;
        ws[WS_FUBETA + c] = (fu_b[c] - fu_mean[c]) * fui + fu_bias[c];
    }
}

__device__ __forceinline__ unsigned int pack_bf16(float a, float b) {
    __hip_bfloat16 ha = __float2bfloat16(a), hb = __float2bfloat16(b);
    return (unsigned int)*(unsigned short*)&ha | ((unsigned int)*(unsigned short*)&hb << 16);
}

// NCHW f32 -> padded NHWC bf16 transpose for rgb & depth, fused with
// global-avg-pool partial sums. One block per (padded row, batch).
__global__ __launch_bounds__(256) void k_nhwc(const float* __restrict__ rgb,
                                              const float* __restrict__ depth,
                                              unsigned int* __restrict__ rgbT,
                                              unsigned int* __restrict__ depthT,
                                              float* __restrict__ part) {
    int yp = blockIdx.x;   // 0..129 padded row
    int b  = blockIdx.y;
    int t  = threadIdx.x;
    unsigned int* dstR = rgbT   + ((size_t)b * 130 + yp) * 130 * 32;  // 32 u32 per pixel
    unsigned int* dstD = depthT + ((size_t)b * 130 + yp) * 130 * 32;

    if (yp == 0 || yp == 129) {           // full zero rows (incl. corners)
        for (int i = t; i < 130 * 32; i += 256) { dstR[i] = 0u; dstD[i] = 0u; }
        return;
    }
    int y = yp - 1;
    if (t < 128) {                        // side border pixels x'=0,129
        int tensor = t >> 6, side = (t >> 5) & 1, j = t & 31;
        unsigned int* d = tensor ? dstD : dstR;
        d[(side ? 129 : 0) * 32 + j] = 0u;
    }

    __shared__ unsigned int lds_t[128 * 17];
    __shared__ float poolacc[4][128];
    int x = t & 127, cpl = t >> 7, w = t >> 6, lane = t & 63;

    #pragma unroll
    for (int ph = 0; ph < 4; ++ph) {
        const float* src = (ph >> 1) ? depth : rgb;
        int chbase = (ph & 1) * 32;
        #pragma unroll
        for (int i = 0; i < 8; ++i) {
            int cpair = i * 2 + cpl;                  // 0..15
            int c = chbase + cpair * 2;               // within-tensor channel
            float v0 = src[(((size_t)b * CB + c    ) * HH + y) * WW + x];
            float v1 = src[(((size_t)b * CB + c + 1) * HH + y) * WW + x];
            lds_t[x * 17 + cpair] = pack_bf16(v0, v1);
            float s0 = v0, s1 = v1;
            #pragma unroll
            for (int off = 32; off; off >>= 1) {
                s0 += __shfl_down(s0, off, 64);
                s1 += __shfl_down(s1, off, 64);
            }
            if (lane == 0) {
                int cc = (ph >> 1) * 64 + c;
                poolacc[w][cc] = s0;
                poolacc[w][cc + 1] = s1;
            }
        }
        __syncthreads();
        {   // store this 32-channel half of each pixel line
            int p = t >> 1, h = t & 1;
            unsigned int vv[8];
            #pragma unroll
            for (int j = 0; j < 8; ++j) vv[j] = lds_t[p * 17 + h * 8 + j];
            unsigned int* dst = (ph >> 1) ? dstD : dstR;
            unsigned int* dp = dst + (p + 1) * 32 + (chbase >> 1) + h * 8;
            uint4 q0 = {vv[0], vv[1], vv[2], vv[3]};
            uint4 q1 = {vv[4], vv[5], vv[6], vv[7]};
            *(uint4*)dp = q0;
            *(uint4*)(dp + 4) = q1;
        }
        __syncthreads();
    }
    if (t < 128) {
        int w0 = 2 * ((t >> 1) & 1);
        part[((size_t)b * 128 + y) * 128 + t] = poolacc[w0][t] + poolacc[w0 + 1][t];
    }
}

__global__ __launch_bounds__(256) void k_pool2(const float* __restrict__ part,
                                               float* __restrict__ ws) {
    int b = blockIdx.x, t = threadIdx.x, cc = t & 127, q = t >> 7;
    float s = 0.f;
    for (int y = q * 64; y < q * 64 + 64; ++y)
        s += part[((size_t)b * 128 + y) * 128 + cc];
    __shared__ float red[2][128];
    red[q][cc] = s;
    __syncthreads();
    if (t < 128)
        ws[WS_POOLED + b * 128 + t] = (red[0][t] + red[1][t]) * (1.f / 16384.f);
}

__global__ void k_hid(const float* __restrict__ w1, const float* __restrict__ b1,
                      float* __restrict__ ws) {
    __shared__ float p[128];
    int b = blockIdx.x, j = threadIdx.x;
    p[j] = ws[WS_POOLED + b * 128 + j];
    __syncthreads();
    if (j < CB) {
        float s = b1[j];
        const float* wr = w1 + j * 128;
        #pragma unroll 8
        for (int i = 0; i < 128; ++i) s += p[i] * wr[i];
        ws[WS_HID + b * CB + j] = fmaxf(s, 0.f);
    }
}

__global__ __launch_bounds__(256) void k_kern(const float* __restrict__ w2, const float* __restrict__ b2,
                                              float* __restrict__ ws) {
    __shared__ float h[CB];
    int b = blockIdx.x, t = threadIdx.x;
    if (t < CB) h[t] = ws[WS_HID + b * CB + t];
    __syncthreads();
    float local = 0.f;
    #pragma unroll
    for (int r9 = 0; r9 < 9; ++r9) {
        int r = t * 9 + r9;
        float s = b2[r];
        const float* wr = w2 + r * CB;
        #pragma unroll 8
        for (int m = 0; m < CB; ++m) s += h[m] * wr[m];
        ws[WS_KERN + b * 2304 + r] = s;
        local += s * s;
    }
    #pragma unroll
    for (int off = 32; off; off >>= 1) local += __shfl_down(local, off, 64);
    if ((t & 63) == 0) ws[WS_SSQ + b * KK + (t >> 6)] = local;
}

__global__ __launch_bounds__(256) void k_wk(float* __restrict__ ws) {
    __shared__ float attn[KK];
    int b = blockIdx.x, t = threadIdx.x;
    if (t == 0) {
        float n[KK], m = -1e30f;
        #pragma unroll
        for (int k = 0; k < KK; ++k) { n[k] = sqrtf(ws[WS_SSQ + b * KK + k]); m = fmaxf(m, n[k]); }
        float e[KK], den = 0.f;
        #pragma unroll
        for (int k = 0; k < KK; ++k) { e[k] = expf(n[k] - m); den += e[k]; }
        float inv = 1.f / den;
        #pragma unroll
        for (int k = 0; k < KK; ++k) attn[k] = e[k] * inv;
    }
    __syncthreads();
    const float* kb = ws + WS_KERN + b * 2304;
    float a0 = attn[0], a1 = attn[1], a2 = attn[2], a3 = attn[3];
    for (int idx = t; idx < 576; idx += 256) {
        float s = a0 * kb[idx] + a1 * kb[576 + idx] + a2 * kb[1152 + idx] + a3 * kb[1728 + idx];
        ws[WS_WK + b * 576 + idx] = s;
    }
}

__global__ __launch_bounds__(256) void k_effw(const float* __restrict__ fu_w, float* __restrict__ ws) {
    int o = blockIdx.x, t = threadIdx.x;
    __shared__ float fw[CB];
    float fi = ws[WS_FUINV + o];
    if (t < CB) {
        fw[t] = fu_w[o * 128 + t] * fi;
        ws[WS_FUW2 + o * CB + t] = fu_w[o * 128 + CB + t] * fi;
    }
    __syncthreads();
    for (int idx = t; idx < 576; idx += 256) {
        float s = 0.f;
        #pragma unroll 8
        for (int c = 0; c < CB; ++c) s += fw[c] * ws[WS_WK + c * 576 + idx];
        ws[WS_EFFW + o * 576 + idx] = s;
    }
}

__global__ void k_prepw(const float* __restrict__ fd_w, float* __restrict__ ws) {
    int e = blockIdx.x * 256 + threadIdx.x;
    unsigned short* wt3 = (unsigned short*)((char*)ws + WT3_BYTE);
    unsigned short* wfd = (unsigned short*)((char*)ws + WFD_BYTE);
    unsigned short* w1o = (unsigned short*)((char*)ws + W1_BYTE);
    if (e < 36864) {
        int tap = e >> 12, rem = e & 4095, o = rem >> 6, ci = rem & 63;
        __hip_bfloat16 h = __float2bfloat16(ws[WS_EFFW + o * 576 + ci * 9 + tap]);
        wt3[e] = *(unsigned short*)&h;
    } else if (e < 73728) {
        int e2 = e - 36864;
        int tap = e2 >> 12, rem = e2 & 4095, o = rem >> 6, ci = rem & 63;
        __hip_bfloat16 h = __float2bfloat16(fd_w[(o * 64 + ci) * 9 + tap] * ws[WS_FDINV + o]);
        wfd[e2] = *(unsigned short*)&h;
    } else if (e < 77824) {
        int e3 = e - 73728;
        __hip_bfloat16 h = __float2bfloat16(ws[WS_FUW2 + e3]);
        w1o[e3] = *(unsigned short*)&h;
    }
}

// ---------------- fused conv kernel ----------------
// Tile 32x8 px. LDS: [10 rows][34 x][8 chunks of 8 bf16] = 43520 B.
// LDS dest is LINEAR (chunk slot cs at lane order); the XOR swizzle
// (cs ^ (x&7)) is applied on the GLOBAL source address (m173 pattern), and the
// same XOR on the ds_read side. Staging uses global_load_lds width=16: no data
// VGPRs, async across the following VALU/MFMA work.

__device__ __forceinline__ void gload_lds16(const void* g, void* l) {
    __builtin_amdgcn_global_load_lds((const __attribute__((address_space(1))) unsigned int*)g,
                                     (__attribute__((address_space(3))) unsigned int*)l, 16, 0, 0);
}

__device__ __forceinline__ void stage_async(const unsigned short* __restrict__ T, int b,
                                            int y0p, int x0p, int t, char* tile) {
    const char* base = (const char*)(T + (((size_t)b * 130 + y0p) * 130 + x0p) * 64);
    #pragma unroll
    for (int it = 0; it < 10; ++it) {
        int n = it * 256 + t;
        int row = n / 272, rem = n - row * 272;
        int xx = rem >> 3, cs = rem & 7;
        gload_lds16(base + (size_t)row * 16640 + xx * 128 + ((cs ^ (xx & 7)) << 4),
                    tile + n * 16);
    }
    if (t < 160) {              // tail chunks 2560..2719
        int n = 2560 + t;
        int row = n / 272, rem = n - row * 272;
        int xx = rem >> 3, cs = rem & 7;
        gload_lds16(base + (size_t)row * 16640 + xx * 128 + ((cs ^ (xx & 7)) << 4),
                    tile + n * 16);
    }
}

__device__ __forceinline__ void conv3x3(f32x4 (&acc)[4][4], const unsigned short* __restrict__ W,
                                        const char* tile, int w, int lx, int lq) {
    #pragma unroll
    for (int tap = 0; tap < 9; ++tap) {
        const int di = tap / 3, dj = tap % 3;
        #pragma unroll
        for (int cb = 0; cb < 2; ++cb) {
            short8 a[4], bf[4];
            #pragma unroll
            for (int mt = 0; mt < 4; ++mt)
                a[mt] = *(const short8*)(W + (tap * 64 + mt * 16 + lx) * 64 + cb * 32 + lq * 8);
            #pragma unroll
            for (int nt = 0; nt < 4; ++nt) {
                int r = nt >> 1, xh = nt & 1;
                int row = 2 * w + r + di;
                int xx = xh * 16 + lx + dj;
                int slot = (row * 34 + xx) * 8 + ((cb * 4 + lq) ^ (xx & 7));
                bf[nt] = *(const short8*)(tile + slot * 16);
            }
            __builtin_amdgcn_s_setprio(1);
            #pragma unroll
            for (int mt = 0; mt < 4; ++mt)
                #pragma unroll
                for (int nt = 0; nt < 4; ++nt)
                    acc[mt][nt] = __builtin_amdgcn_mfma_f32_16x16x32_bf16(a[mt], bf[nt], acc[mt][nt], 0, 0, 0);
            __builtin_amdgcn_s_setprio(0);
        }
    }
}

__global__ __launch_bounds__(256, 3) void k_fused(const unsigned short* __restrict__ rgbT,
                                                  const unsigned short* __restrict__ depthT,
                                                  const float* __restrict__ ws,
                                                  float* __restrict__ out) {
    __shared__ __align__(16) char tile[43520];
    // bijective XCD swizzle over 4096 blocks (4096 % 8 == 0): each XCD gets a
    // contiguous 512-block chunk = 8 full batches -> halo-sharing neighbors co-XCD.
    int id = blockIdx.x;
    int swz = (id & 7) * 512 + (id >> 3);
    int bx = swz & 3, by = (swz >> 2) & 15, b = swz >> 6;
    int x0 = bx * 32, y0 = by * 8;
    int t = threadIdx.x, lane = t & 63, w = t >> 6;
    int lx = lane & 15, lq = lane >> 4;

    const unsigned short* wfd = (const unsigned short*)((const char*)ws + WFD_BYTE);
    const unsigned short* wt3 = (const unsigned short*)((const char*)ws + WT3_BYTE);
    const unsigned short* w1o = (const unsigned short*)((const char*)ws + W1_BYTE);

    // ---- issue depth tile loads (async into LDS) ----
    stage_async(depthT, b, y0, x0, t, tile);

    f32x4 facc[4][4];
    #pragma unroll
    for (int mt = 0; mt < 4; ++mt) {
        f32x4 bi;
        #pragma unroll
        for (int i = 0; i < 4; ++i) bi[i] = ws[WS_FDBETA + mt * 16 + lq * 4 + i];
        #pragma unroll
        for (int nt = 0; nt < 4; ++nt) facc[mt][nt] = bi;
    }
    __syncthreads();   // depth tile resident

    // ---- freq = relu(BN(conv3x3(depth))) in registers ----
    conv3x3(facc, wfd, tile, w, lx, lq);
    __syncthreads();   // all depth-tile reads done

    // ---- issue rgb tile loads; latency hides under fr-build + 1x1 ----
    stage_async(rgbT, b, y0, x0, t, tile);

    // ---- build 1x1 B-fragments from facc via cross-lane redistribution ----
    short8 fr[2][4];
    {
        int sA = lx + ((lq & 1) ? 32 : 0);
        int sB = sA + 16;
        bool hi = (lq >> 1) != 0;
        #pragma unroll
        for (int nt = 0; nt < 4; ++nt) {
            unsigned int pk[4][2];
            #pragma unroll
            for (int mt = 0; mt < 4; ++mt) {
                float v0 = fmaxf(facc[mt][nt][0], 0.f), v1 = fmaxf(facc[mt][nt][1], 0.f);
                float v2 = fmaxf(facc[mt][nt][2], 0.f), v3 = fmaxf(facc[mt][nt][3], 0.f);
                pk[mt][0] = pack_bf16(v0, v1);
                pk[mt][1] = pack_bf16(v2, v3);
            }
            #pragma unroll
            for (int cb = 0; cb < 2; ++cb) {
                unsigned int a0m0 = __shfl((int)pk[cb * 2][0], sA, 64);
                unsigned int a1m0 = __shfl((int)pk[cb * 2][1], sA, 64);
                unsigned int a0m1 = __shfl((int)pk[cb * 2 + 1][0], sA, 64);
                unsigned int a1m1 = __shfl((int)pk[cb * 2 + 1][1], sA, 64);
                unsigned int b0m0 = __shfl((int)pk[cb * 2][0], sB, 64);
                unsigned int b1m0 = __shfl((int)pk[cb * 2][1], sB, 64);
                unsigned int b0m1 = __shfl((int)pk[cb * 2 + 1][0], sB, 64);
                unsigned int b1m1 = __shfl((int)pk[cb * 2 + 1][1], sB, 64);
                union { unsigned int u[4]; short8 s; } U;
                U.u[0] = hi ? a0m1 : a0m0;
                U.u[1] = hi ? a1m1 : a1m0;
                U.u[2] = hi ? b0m1 : b0m0;
                U.u[3] = hi ? b1m1 : b1m0;
                fr[cb][nt] = U.s;
            }
        }
    }

    // ---- acc init + 1x1 over freq fragments (register-only) ----
    f32x4 acc[4][4];
    #pragma unroll
    for (int mt = 0; mt < 4; ++mt) {
        f32x4 bi;
        #pragma unroll
        for (int i = 0; i < 4; ++i) bi[i] = ws[WS_FUBETA + mt * 16 + lq * 4 + i];
        #pragma unroll
        for (int nt = 0; nt < 4; ++nt) acc[mt][nt] = bi;
    }
    #pragma unroll
    for (int cb = 0; cb < 2; ++cb) {
        short8 a[4];
        #pragma unroll
        for (int mt = 0; mt < 4; ++mt)
            a[mt] = *(const short8*)(w1o + (mt * 16 + lx) * 64 + cb * 32 + lq * 8);
        __builtin_amdgcn_s_setprio(1);
        #pragma unroll
        for (int mt = 0; mt < 4; ++mt)
            #pragma unroll
            for (int nt = 0; nt < 4; ++nt)
                acc[mt][nt] = __builtin_amdgcn_mfma_f32_16x16x32_bf16(a[mt], fr[cb][nt], acc[mt][nt], 0, 0, 0);
        __builtin_amdgcn_s_setprio(0);
    }
    __syncthreads();   // rgb tile resident

    // ---- dynamic conv over rgb ----
    conv3x3(acc, wt3, tile, w, lx, lq);

    // ---- epilogue: NCHW f32 stores, full 128B lines within one wave ----
    #pragma unroll
    for (int nt = 0; nt < 4; ++nt) {
        int r = nt >> 1, xh = nt & 1;
        int y = y0 + 2 * w + r, x = x0 + xh * 16 + lx;
        #pragma unroll
        for (int mt = 0; mt < 4; ++mt) {
            int o = mt * 16 + lq * 4;
            #pragma unroll
            for (int i = 0; i < 4; ++i)
                out[(((size_t)b * CB + (o + i)) * HH + y) * WW + x] = fmaxf(acc[mt][nt][i], 0.f);
        }
    }
}

// ---------------- launch ----------------

extern "C" void kernel_launch(void* const* d_in, const int* in_sizes, int n_in,
                              void* d_out, int out_size, void* d_ws, size_t ws_size,
                              hipStream_t stream) {
    const float* rgb      = (const float*)d_in[0];
    const float* depth    = (const float*)d_in[1];
    const float* w1       = (const float*)d_in[2];
    const float* b1       = (const float*)d_in[3];
    const float* w2       = (const float*)d_in[4];
    const float* b2       = (const float*)d_in[5];
    const float* fd_w     = (const float*)d_in[6];
    const float* fd_b     = (const float*)d_in[7];
    const float* fd_scale = (const float*)d_in[8];
    const float* fd_bias  = (const float*)d_in[9];
    const float* fd_mean  = (const float*)d_in[10];
    const float* fd_var   = (const float*)d_in[11];
    const float* fu_w     = (const float*)d_in[12];
    const float* fu_b     = (const float*)d_in[13];
    const float* fu_scale = (const float*)d_in[14];
    const float* fu_bias  = (const float*)d_in[15];
    const float* fu_mean  = (const float*)d_in[16];
    const float* fu_var   = (const float*)d_in[17];

    float* ws = (float*)d_ws;
    float* part = (float*)((char*)d_ws + WS_PART_BYTE);
    unsigned int* depthT = (unsigned int*)((char*)d_ws + WS_DEPTHT_BYTE);
    unsigned int* rgbT   = (unsigned int*)((char*)d_ws + WS_RGBT_BYTE);
    float* out = (float*)d_out;

    k_consts<<<1, 64, 0, stream>>>(fd_scale, fd_bias, fd_mean, fd_var, fd_b,
                                   fu_scale, fu_bias, fu_mean, fu_var, fu_b, ws);
    k_nhwc<<<dim3(130, 64), 256, 0, stream>>>(rgb, depth, rgbT, depthT, part);
    k_pool2<<<CB, 256, 0, stream>>>(part, ws);
    k_hid<<<CB, 128, 0, stream>>>(w1, b1, ws);
    k_kern<<<CB, 256, 0, stream>>>(w2, b2, ws);
    k_wk<<<CB, 256, 0, stream>>>(ws);
    k_effw<<<CB, 256, 0, stream>>>(fu_w, ws);
    k_prepw<<<304, 256, 0, stream>>>(fd_w, ws);

    k_fused<<<4096, 256, 0, stream>>>((const unsigned short*)rgbT,
                                      (const unsigned short*)depthT, ws, out);
}

// Round 5
// 788.803 us; speedup vs baseline: 1.0117x; 1.0117x over previous
//
#include <hip/hip_runtime.h>
#include <hip/hip_bf16.h>

#define CB 64      // B == C == 64
#define HH 128
#define WW 128
#define KK 4
#define EPSV 1e-5f
#define HWSZ (HH*WW)

using f32x4  = __attribute__((ext_vector_type(4))) float;
using short8 = __attribute__((ext_vector_type(8))) short;

// ---- workspace layout ----
// float element offsets (small area, < 4 MiB):
static constexpr size_t WS_POOLED = 0;          // [64][128]
static constexpr size_t WS_HID    = 8192;       // [64][64]
static constexpr size_t WS_KERN   = 12288;      // [64][2304] (dead after k_wk; bf16 weights reuse bytes)
static constexpr size_t WS_SSQ    = 159744;     // [64][4]
static constexpr size_t WS_WK     = 160000;     // [64][576]
static constexpr size_t WS_EFFW   = 196864;     // [64][576]
static constexpr size_t WS_FUW2   = 233728;     // [64][64]
static constexpr size_t WS_FDINV  = 237824;     // [64]
static constexpr size_t WS_FDBETA = 237888;     // [64]
static constexpr size_t WS_FUINV  = 237952;     // [64]
static constexpr size_t WS_FUBETA = 238016;     // [64]
// byte offsets inside dead WS_KERN byte range (49152..638976):
static constexpr size_t WT3_BYTE = 49152;              // bf16 [9][64][64]
static constexpr size_t WFD_BYTE = 49152 + 73728;      // bf16 [9][64][64]
static constexpr size_t W1_BYTE  = 49152 + 147456;     // bf16 [64][64]
// big buffers:
static constexpr size_t WS_PART_BYTE   = 4u << 20;     // f32 [64][128][128] partial row sums
static constexpr size_t WS_DEPTHT_BYTE = 8u << 20;     // bf16 [64][130][130][64] zero-padded (132 MB)
static constexpr size_t WS_RGBT_BYTE   = 140u << 20;   // bf16 [64][130][130][64] zero-padded

// ---------------- small kernels (verified rounds 1-4) ----------------

__global__ void k_consts(const float* __restrict__ fd_scale, const float* __restrict__ fd_bias,
                         const float* __restrict__ fd_mean, const float* __restrict__ fd_var,
                         const float* __restrict__ fd_b,
                         const float* __restrict__ fu_scale, const float* __restrict__ fu_bias,
                         const float* __restrict__ fu_mean, const float* __restrict__ fu_var,
                         const float* __restrict__ fu_b,
                         float* __restrict__ ws) {
    int c = threadIdx.x;
    if (c < CB) {
        float fdi = fd_scale[c] / sqrtf(fd_var[c] + EPSV);
        ws[WS_FDINV + c]  = fdi;
        ws[WS_FDBETA + c] = (fd_b[c] - fd_mean[c]) * fdi + fd_bias[c];
        float fui = fu_scale[c] / sqrtf(fu_var[c] + EPSV);
        ws[WS_FUINV + c]  = fui;
        ws[WS_FUBETA + c] = (fu_b[c] - fu_mean[c]) * fui + fu_bias[c];
    }
}

__device__ __forceinline__ unsigned int pack_bf16(float a, float b) {
    __hip_bfloat16 ha = __float2bfloat16(a), hb = __float2bfloat16(b);
    return (unsigned int)*(unsigned short*)&ha | ((unsigned int)*(unsigned short*)&hb << 16);
}

// NCHW f32 -> padded NHWC bf16 transpose for rgb & depth, fused with
// global-avg-pool partial sums. One block per (padded row, batch).
__global__ __launch_bounds__(256) void k_nhwc(const float* __restrict__ rgb,
                                              const float* __restrict__ depth,
                                              unsigned int* __restrict__ rgbT,
                                              unsigned int* __restrict__ depthT,
                                              float* __restrict__ part) {
    int yp = blockIdx.x;   // 0..129 padded row
    int b  = blockIdx.y;
    int t  = threadIdx.x;
    unsigned int* dstR = rgbT   + ((size_t)b * 130 + yp) * 130 * 32;  // 32 u32 per pixel
    unsigned int* dstD = depthT + ((size_t)b * 130 + yp) * 130 * 32;

    if (yp == 0 || yp == 129) {           // full zero rows (incl. corners)
        for (int i = t; i < 130 * 32; i += 256) { dstR[i] = 0u; dstD[i] = 0u; }
        return;
    }
    int y = yp - 1;
    if (t < 128) {                        // side border pixels x'=0,129
        int tensor = t >> 6, side = (t >> 5) & 1, j = t & 31;
        unsigned int* d = tensor ? dstD : dstR;
        d[(side ? 129 : 0) * 32 + j] = 0u;
    }

    __shared__ unsigned int lds_t[128 * 17];
    __shared__ float poolacc[4][128];
    int x = t & 127, cpl = t >> 7, w = t >> 6, lane = t & 63;

    #pragma unroll
    for (int ph = 0; ph < 4; ++ph) {
        const float* src = (ph >> 1) ? depth : rgb;
        int chbase = (ph & 1) * 32;
        #pragma unroll
        for (int i = 0; i < 8; ++i) {
            int cpair = i * 2 + cpl;                  // 0..15
            int c = chbase + cpair * 2;               // within-tensor channel
            float v0 = src[(((size_t)b * CB + c    ) * HH + y) * WW + x];
            float v1 = src[(((size_t)b * CB + c + 1) * HH + y) * WW + x];
            lds_t[x * 17 + cpair] = pack_bf16(v0, v1);
            float s0 = v0, s1 = v1;
            #pragma unroll
            for (int off = 32; off; off >>= 1) {
                s0 += __shfl_down(s0, off, 64);
                s1 += __shfl_down(s1, off, 64);
            }
            if (lane == 0) {
                int cc = (ph >> 1) * 64 + c;
                poolacc[w][cc] = s0;
                poolacc[w][cc + 1] = s1;
            }
        }
        __syncthreads();
        {   // store this 32-channel half of each pixel line
            int p = t >> 1, h = t & 1;
            unsigned int vv[8];
            #pragma unroll
            for (int j = 0; j < 8; ++j) vv[j] = lds_t[p * 17 + h * 8 + j];
            unsigned int* dst = (ph >> 1) ? dstD : dstR;
            unsigned int* dp = dst + (p + 1) * 32 + (chbase >> 1) + h * 8;
            uint4 q0 = {vv[0], vv[1], vv[2], vv[3]};
            uint4 q1 = {vv[4], vv[5], vv[6], vv[7]};
            *(uint4*)dp = q0;
            *(uint4*)(dp + 4) = q1;
        }
        __syncthreads();
    }
    if (t < 128) {
        int w0 = 2 * ((t >> 1) & 1);
        part[((size_t)b * 128 + y) * 128 + t] = poolacc[w0][t] + poolacc[w0 + 1][t];
    }
}

__global__ __launch_bounds__(256) void k_pool2(const float* __restrict__ part,
                                               float* __restrict__ ws) {
    int b = blockIdx.x, t = threadIdx.x, cc = t & 127, q = t >> 7;
    float s = 0.f;
    for (int y = q * 64; y < q * 64 + 64; ++y)
        s += part[((size_t)b * 128 + y) * 128 + cc];
    __shared__ float red[2][128];
    red[q][cc] = s;
    __syncthreads();
    if (t < 128)
        ws[WS_POOLED + b * 128 + t] = (red[0][t] + red[1][t]) * (1.f / 16384.f);
}

__global__ void k_hid(const float* __restrict__ w1, const float* __restrict__ b1,
                      float* __restrict__ ws) {
    __shared__ float p[128];
    int b = blockIdx.x, j = threadIdx.x;
    p[j] = ws[WS_POOLED + b * 128 + j];
    __syncthreads();
    if (j < CB) {
        float s = b1[j];
        const float* wr = w1 + j * 128;
        #pragma unroll 8
        for (int i = 0; i < 128; ++i) s += p[i] * wr[i];
        ws[WS_HID + b * CB + j] = fmaxf(s, 0.f);
    }
}

__global__ __launch_bounds__(256) void k_kern(const float* __restrict__ w2, const float* __restrict__ b2,
                                              float* __restrict__ ws) {
    __shared__ float h[CB];
    int b = blockIdx.x, t = threadIdx.x;
    if (t < CB) h[t] = ws[WS_HID + b * CB + t];
    __syncthreads();
    float local = 0.f;
    #pragma unroll
    for (int r9 = 0; r9 < 9; ++r9) {
        int r = t * 9 + r9;
        float s = b2[r];
        const float* wr = w2 + r * CB;
        #pragma unroll 8
        for (int m = 0; m < CB; ++m) s += h[m] * wr[m];
        ws[WS_KERN + b * 2304 + r] = s;
        local += s * s;
    }
    #pragma unroll
    for (int off = 32; off; off >>= 1) local += __shfl_down(local, off, 64);
    if ((t & 63) == 0) ws[WS_SSQ + b * KK + (t >> 6)] = local;
}

__global__ __launch_bounds__(256) void k_wk(float* __restrict__ ws) {
    __shared__ float attn[KK];
    int b = blockIdx.x, t = threadIdx.x;
    if (t == 0) {
        float n[KK], m = -1e30f;
        #pragma unroll
        for (int k = 0; k < KK; ++k) { n[k] = sqrtf(ws[WS_SSQ + b * KK + k]); m = fmaxf(m, n[k]); }
        float e[KK], den = 0.f;
        #pragma unroll
        for (int k = 0; k < KK; ++k) { e[k] = expf(n[k] - m); den += e[k]; }
        float inv = 1.f / den;
        #pragma unroll
        for (int k = 0; k < KK; ++k) attn[k] = e[k] * inv;
    }
    __syncthreads();
    const float* kb = ws + WS_KERN + b * 2304;
    float a0 = attn[0], a1 = attn[1], a2 = attn[2], a3 = attn[3];
    for (int idx = t; idx < 576; idx += 256) {
        float s = a0 * kb[idx] + a1 * kb[576 + idx] + a2 * kb[1152 + idx] + a3 * kb[1728 + idx];
        ws[WS_WK + b * 576 + idx] = s;
    }
}

__global__ __launch_bounds__(256) void k_effw(const float* __restrict__ fu_w, float* __restrict__ ws) {
    int o = blockIdx.x, t = threadIdx.x;
    __shared__ float fw[CB];
    float fi = ws[WS_FUINV + o];
    if (t < CB) {
        fw[t] = fu_w[o * 128 + t] * fi;
        ws[WS_FUW2 + o * CB + t] = fu_w[o * 128 + CB + t] * fi;
    }
    __syncthreads();
    for (int idx = t; idx < 576; idx += 256) {
        float s = 0.f;
        #pragma unroll 8
        for (int c = 0; c < CB; ++c) s += fw[c] * ws[WS_WK + c * 576 + idx];
        ws[WS_EFFW + o * 576 + idx] = s;
    }
}

__global__ void k_prepw(const float* __restrict__ fd_w, float* __restrict__ ws) {
    int e = blockIdx.x * 256 + threadIdx.x;
    unsigned short* wt3 = (unsigned short*)((char*)ws + WT3_BYTE);
    unsigned short* wfd = (unsigned short*)((char*)ws + WFD_BYTE);
    unsigned short* w1o = (unsigned short*)((char*)ws + W1_BYTE);
    if (e < 36864) {
        int tap = e >> 12, rem = e & 4095, o = rem >> 6, ci = rem & 63;
        __hip_bfloat16 h = __float2bfloat16(ws[WS_EFFW + o * 576 + ci * 9 + tap]);
        wt3[e] = *(unsigned short*)&h;
    } else if (e < 73728) {
        int e2 = e - 36864;
        int tap = e2 >> 12, rem = e2 & 4095, o = rem >> 6, ci = rem & 63;
        __hip_bfloat16 h = __float2bfloat16(fd_w[(o * 64 + ci) * 9 + tap] * ws[WS_FDINV + o]);
        wfd[e2] = *(unsigned short*)&h;
    } else if (e < 77824) {
        int e3 = e - 73728;
        __hip_bfloat16 h = __float2bfloat16(ws[WS_FUW2 + e3]);
        w1o[e3] = *(unsigned short*)&h;
    }
}

// ---------------- fused conv kernel ----------------
// Tile 32x8 px. LDS: [10 rows][34 x][8 chunks of 8 bf16] = 43520 B.
// LDS dest is LINEAR; the XOR swizzle (cs ^ (x&7)) is applied on the GLOBAL
// source address (m173 pattern) and mirrored on the ds_read side. Staging uses
// global_load_lds width=16 (no data VGPRs, async).

__device__ __forceinline__ void gload_lds16(const void* g, void* l) {
    __builtin_amdgcn_global_load_lds((const __attribute__((address_space(1))) unsigned int*)g,
                                     (__attribute__((address_space(3))) unsigned int*)l, 16, 0, 0);
}

__device__ __forceinline__ void stage_async(const unsigned short* __restrict__ T, int b,
                                            int y0p, int x0p, int t, char* tile) {
    const char* base = (const char*)(T + (((size_t)b * 130 + y0p) * 130 + x0p) * 64);
    #pragma unroll
    for (int it = 0; it < 10; ++it) {
        int n = it * 256 + t;
        int row = n / 272, rem = n - row * 272;
        int xx = rem >> 3, cs = rem & 7;
        gload_lds16(base + (size_t)row * 16640 + xx * 128 + ((cs ^ (xx & 7)) << 4),
                    tile + n * 16);
    }
    if (t < 160) {              // tail chunks 2560..2719
        int n = 2560 + t;
        int row = n / 272, rem = n - row * 272;
        int xx = rem >> 3, cs = rem & 7;
        gload_lds16(base + (size_t)row * 16640 + xx * 128 + ((cs ^ (xx & 7)) << 4),
                    tile + n * 16);
    }
}

__device__ __forceinline__ void conv3x3(f32x4 (&acc)[4][4], const unsigned short* __restrict__ W,
                                        const char* tile, int w, int lx, int lq) {
    #pragma unroll
    for (int tap = 0; tap < 9; ++tap) {
        const int di = tap / 3, dj = tap % 3;
        #pragma unroll
        for (int cb = 0; cb < 2; ++cb) {
            short8 a[4], bf[4];
            #pragma unroll
            for (int mt = 0; mt < 4; ++mt)
                a[mt] = *(const short8*)(W + (tap * 64 + mt * 16 + lx) * 64 + cb * 32 + lq * 8);
            #pragma unroll
            for (int nt = 0; nt < 4; ++nt) {
                int r = nt >> 1, xh = nt & 1;
                int row = 2 * w + r + di;
                int xx = xh * 16 + lx + dj;
                int slot = (row * 34 + xx) * 8 + ((cb * 4 + lq) ^ (xx & 7));
                bf[nt] = *(const short8*)(tile + slot * 16);
            }
            __builtin_amdgcn_s_setprio(1);
            #pragma unroll
            for (int mt = 0; mt < 4; ++mt)
                #pragma unroll
                for (int nt = 0; nt < 4; ++nt)
                    acc[mt][nt] = __builtin_amdgcn_mfma_f32_16x16x32_bf16(a[mt], bf[nt], acc[mt][nt], 0, 0, 0);
            __builtin_amdgcn_s_setprio(0);
        }
    }
}

__global__ __launch_bounds__(256, 3) void k_fused(const unsigned short* __restrict__ rgbT,
                                                  const unsigned short* __restrict__ depthT,
                                                  const float* __restrict__ ws,
                                                  float* __restrict__ out) {
    __shared__ __align__(16) char tile[43520];
    int b = blockIdx.z;
    int x0 = blockIdx.x * 32, y0 = blockIdx.y * 8;
    int t = threadIdx.x, lane = t & 63, w = t >> 6;
    int lx = lane & 15, lq = lane >> 4;

    const unsigned short* wfd = (const unsigned short*)((const char*)ws + WFD_BYTE);
    const unsigned short* wt3 = (const unsigned short*)((const char*)ws + WT3_BYTE);
    const unsigned short* w1o = (const unsigned short*)((const char*)ws + W1_BYTE);

    // ---- issue depth tile loads (async into LDS) ----
    stage_async(depthT, b, y0, x0, t, tile);

    f32x4 facc[4][4];
    #pragma unroll
    for (int mt = 0; mt < 4; ++mt) {
        f32x4 bi;
        #pragma unroll
        for (int i = 0; i < 4; ++i) bi[i] = ws[WS_FDBETA + mt * 16 + lq * 4 + i];
        #pragma unroll
        for (int nt = 0; nt < 4; ++nt) facc[mt][nt] = bi;
    }
    __syncthreads();   // depth tile resident (vmcnt drained by barrier)

    // ---- freq = relu(BN(conv3x3(depth))) in registers ----
    conv3x3(facc, wfd, tile, w, lx, lq);
    __syncthreads();   // all depth-tile reads done

    // ---- build 1x1 B-fragments from facc (facc dies here) ----
    short8 fr[2][4];
    {
        int sA = lx + ((lq & 1) ? 32 : 0);
        int sB = sA + 16;
        bool hi = (lq >> 1) != 0;
        #pragma unroll
        for (int nt = 0; nt < 4; ++nt) {
            unsigned int pk[4][2];
            #pragma unroll
            for (int mt = 0; mt < 4; ++mt) {
                float v0 = fmaxf(facc[mt][nt][0], 0.f), v1 = fmaxf(facc[mt][nt][1], 0.f);
                float v2 = fmaxf(facc[mt][nt][2], 0.f), v3 = fmaxf(facc[mt][nt][3], 0.f);
                pk[mt][0] = pack_bf16(v0, v1);
                pk[mt][1] = pack_bf16(v2, v3);
            }
            #pragma unroll
            for (int cb = 0; cb < 2; ++cb) {
                unsigned int a0m0 = __shfl((int)pk[cb * 2][0], sA, 64);
                unsigned int a1m0 = __shfl((int)pk[cb * 2][1], sA, 64);
                unsigned int a0m1 = __shfl((int)pk[cb * 2 + 1][0], sA, 64);
                unsigned int a1m1 = __shfl((int)pk[cb * 2 + 1][1], sA, 64);
                unsigned int b0m0 = __shfl((int)pk[cb * 2][0], sB, 64);
                unsigned int b1m0 = __shfl((int)pk[cb * 2][1], sB, 64);
                unsigned int b0m1 = __shfl((int)pk[cb * 2 + 1][0], sB, 64);
                unsigned int b1m1 = __shfl((int)pk[cb * 2 + 1][1], sB, 64);
                union { unsigned int u[4]; short8 s; } U;
                U.u[0] = hi ? a0m1 : a0m0;
                U.u[1] = hi ? a1m1 : a1m0;
                U.u[2] = hi ? b0m1 : b0m0;
                U.u[3] = hi ? b1m1 : b1m0;
                fr[cb][nt] = U.s;
            }
        }
    }

    // ---- issue rgb tile loads now (facc dead -> low liveness) ----
    stage_async(rgbT, b, y0, x0, t, tile);

    // ---- acc init + 1x1 over freq fragments (register-only, hides load latency) ----
    f32x4 acc[4][4];
    #pragma unroll
    for (int mt = 0; mt < 4; ++mt) {
        f32x4 bi;
        #pragma unroll
        for (int i = 0; i < 4; ++i) bi[i] = ws[WS_FUBETA + mt * 16 + lq * 4 + i];
        #pragma unroll
        for (int nt = 0; nt < 4; ++nt) acc[mt][nt] = bi;
    }
    #pragma unroll
    for (int cb = 0; cb < 2; ++cb) {
        short8 a[4];
        #pragma unroll
        for (int mt = 0; mt < 4; ++mt)
            a[mt] = *(const short8*)(w1o + (mt * 16 + lx) * 64 + cb * 32 + lq * 8);
        __builtin_amdgcn_s_setprio(1);
        #pragma unroll
        for (int mt = 0; mt < 4; ++mt)
            #pragma unroll
            for (int nt = 0; nt < 4; ++nt)
                acc[mt][nt] = __builtin_amdgcn_mfma_f32_16x16x32_bf16(a[mt], fr[cb][nt], acc[mt][nt], 0, 0, 0);
        __builtin_amdgcn_s_setprio(0);
    }
    __syncthreads();   // rgb tile resident

    // ---- dynamic conv over rgb ----
    conv3x3(acc, wt3, tile, w, lx, lq);
    __syncthreads();   // all tile reads done; LDS free for epilogue reuse

    // ---- epilogue: per-wave LDS transpose, then full-128B-line stores ----
    // slab stride 36 floats: write banks (16lq+lx) 2-way, read banks 2-way.
    float* slab = (float*)tile + w * 2304;    // 64*36 floats = 9216 B per wave
    int og = lane >> 5, xi = lane & 31;
    #pragma unroll
    for (int r = 0; r < 2; ++r) {
        #pragma unroll
        for (int mt = 0; mt < 4; ++mt)
            #pragma unroll
            for (int xh = 0; xh < 2; ++xh) {
                int nt = r * 2 + xh;
                #pragma unroll
                for (int i = 0; i < 4; ++i)
                    slab[(mt * 16 + lq * 4 + i) * 36 + xh * 16 + lx] =
                        fmaxf(acc[mt][nt][i], 0.f);
            }
        int y = y0 + 2 * w + r;
        size_t rowbase = ((size_t)b * CB * HH + y) * WW + x0;
        #pragma unroll
        for (int k2 = 0; k2 < 32; ++k2) {
            int o = k2 * 2 + og;          // each store instr: 2 rows x 32 x = 2 full lines
            out[rowbase + (size_t)o * HWSZ + xi] = slab[o * 36 + xi];
        }
    }
}

// ---------------- launch ----------------

extern "C" void kernel_launch(void* const* d_in, const int* in_sizes, int n_in,
                              void* d_out, int out_size, void* d_ws, size_t ws_size,
                              hipStream_t stream) {
    const float* rgb      = (const float*)d_in[0];
    const float* depth    = (const float*)d_in[1];
    const float* w1       = (const float*)d_in[2];
    const float* b1       = (const float*)d_in[3];
    const float* w2       = (const float*)d_in[4];
    const float* b2       = (const float*)d_in[5];
    const float* fd_w     = (const float*)d_in[6];
    const float* fd_b     = (const float*)d_in[7];
    const float* fd_scale = (const float*)d_in[8];
    const float* fd_bias  = (const float*)d_in[9];
    const float* fd_mean  = (const float*)d_in[10];
    const float* fd_var   = (const float*)d_in[11];
    const float* fu_w     = (const float*)d_in[12];
    const float* fu_b     = (const float*)d_in[13];
    const float* fu_scale = (const float*)d_in[14];
    const float* fu_bias  = (const float*)d_in[15];
    const float* fu_mean  = (const float*)d_in[16];
    const float* fu_var   = (const float*)d_in[17];

    float* ws = (float*)d_ws;
    float* part = (float*)((char*)d_ws + WS_PART_BYTE);
    unsigned int* depthT = (unsigned int*)((char*)d_ws + WS_DEPTHT_BYTE);
    unsigned int* rgbT   = (unsigned int*)((char*)d_ws + WS_RGBT_BYTE);
    float* out = (float*)d_out;

    k_consts<<<1, 64, 0, stream>>>(fd_scale, fd_bias, fd_mean, fd_var, fd_b,
                                   fu_scale, fu_bias, fu_mean, fu_var, fu_b, ws);
    k_nhwc<<<dim3(130, 64), 256, 0, stream>>>(rgb, depth, rgbT, depthT, part);
    k_pool2<<<CB, 256, 0, stream>>>(part, ws);
    k_hid<<<CB, 128, 0, stream>>>(w1, b1, ws);
    k_kern<<<CB, 256, 0, stream>>>(w2, b2, ws);
    k_wk<<<CB, 256, 0, stream>>>(ws);
    k_effw<<<CB, 256, 0, stream>>>(fu_w, ws);
    k_prepw<<<304, 256, 0, stream>>>(fd_w, ws);

    dim3 grid(WW / 32, HH / 8, CB);
    k_fused<<<grid, 256, 0, stream>>>((const unsigned short*)rgbT,
                                      (const unsigned short*)depthT, ws, out);
}

// Round 6
// 565.685 us; speedup vs baseline: 1.4108x; 1.3944x over previous
//
#include <hip/hip_runtime.h>
#include <hip/hip_bf16.h>

#define CB 64      // B == C == 64
#define HH 128
#define WW 128
#define KK 4
#define EPSV 1e-5f
#define HWSZ (HH*WW)

using f32x4  = __attribute__((ext_vector_type(4))) float;
using short8 = __attribute__((ext_vector_type(8))) short;

// ---- workspace layout ----
static constexpr size_t WS_POOLED = 0;          // [64][128]
static constexpr size_t WS_HID    = 8192;       // [64][64]
static constexpr size_t WS_KERN   = 12288;      // [64][2304] (dead after k_wk; bf16 weights reuse bytes)
static constexpr size_t WS_SSQ    = 159744;     // [64][4]
static constexpr size_t WS_WK     = 160000;     // [64][576]
static constexpr size_t WS_EFFW   = 196864;     // [64][576]
static constexpr size_t WS_FUW2   = 233728;     // [64][64]
static constexpr size_t WS_FDINV  = 237824;     // [64]
static constexpr size_t WS_FDBETA = 237888;     // [64]
static constexpr size_t WS_FUINV  = 237952;     // [64]
static constexpr size_t WS_FUBETA = 238016;     // [64]
// byte offsets inside dead WS_KERN byte range (49152..638976):
static constexpr size_t WT3_BYTE = 49152;              // bf16 [9][64][64]
static constexpr size_t WFD_BYTE = 49152 + 73728;      // bf16 [9][64][64]
static constexpr size_t W1_BYTE  = 49152 + 147456;     // bf16 [64][64]
// big buffers:
static constexpr size_t WS_PART_BYTE   = 4u << 20;     // f32 [64][128][128] partial row sums
static constexpr size_t WS_DEPTHT_BYTE = 8u << 20;     // bf16 [64][130][130][64] zero-padded
static constexpr size_t WS_RGBT_BYTE   = 140u << 20;   // bf16 [64][130][130][64] zero-padded

// ---------------- small kernels (verified rounds 1-5) ----------------

__global__ void k_consts(const float* __restrict__ fd_scale, const float* __restrict__ fd_bias,
                         const float* __restrict__ fd_mean, const float* __restrict__ fd_var,
                         const float* __restrict__ fd_b,
                         const float* __restrict__ fu_scale, const float* __restrict__ fu_bias,
                         const float* __restrict__ fu_mean, const float* __restrict__ fu_var,
                         const float* __restrict__ fu_b,
                         float* __restrict__ ws) {
    int c = threadIdx.x;
    if (c < CB) {
        float fdi = fd_scale[c] / sqrtf(fd_var[c] + EPSV);
        ws[WS_FDINV + c]  = fdi;
        ws[WS_FDBETA + c] = (fd_b[c] - fd_mean[c]) * fdi + fd_bias[c];
        float fui = fu_scale[c] / sqrtf(fu_var[c] + EPSV);
        ws[WS_FUINV + c]  = fui;
        ws[WS_FUBETA + c] = (fu_b[c] - fu_mean[c]) * fui + fu_bias[c];
    }
}

__device__ __forceinline__ unsigned int pack_bf16(float a, float b) {
    __hip_bfloat16 ha = __float2bfloat16(a), hb = __float2bfloat16(b);
    return (unsigned int)*(unsigned short*)&ha | ((unsigned int)*(unsigned short*)&hb << 16);
}

__global__ __launch_bounds__(256) void k_nhwc(const float* __restrict__ rgb,
                                              const float* __restrict__ depth,
                                              unsigned int* __restrict__ rgbT,
                                              unsigned int* __restrict__ depthT,
                                              float* __restrict__ part) {
    int yp = blockIdx.x;   // 0..129 padded row
    int b  = blockIdx.y;
    int t  = threadIdx.x;
    unsigned int* dstR = rgbT   + ((size_t)b * 130 + yp) * 130 * 32;
    unsigned int* dstD = depthT + ((size_t)b * 130 + yp) * 130 * 32;

    if (yp == 0 || yp == 129) {
        for (int i = t; i < 130 * 32; i += 256) { dstR[i] = 0u; dstD[i] = 0u; }
        return;
    }
    int y = yp - 1;
    if (t < 128) {
        int tensor = t >> 6, side = (t >> 5) & 1, j = t & 31;
        unsigned int* d = tensor ? dstD : dstR;
        d[(side ? 129 : 0) * 32 + j] = 0u;
    }

    __shared__ unsigned int lds_t[128 * 17];
    __shared__ float poolacc[4][128];
    int x = t & 127, cpl = t >> 7, w = t >> 6, lane = t & 63;

    #pragma unroll
    for (int ph = 0; ph < 4; ++ph) {
        const float* src = (ph >> 1) ? depth : rgb;
        int chbase = (ph & 1) * 32;
        #pragma unroll
        for (int i = 0; i < 8; ++i) {
            int cpair = i * 2 + cpl;
            int c = chbase + cpair * 2;
            float v0 = src[(((size_t)b * CB + c    ) * HH + y) * WW + x];
            float v1 = src[(((size_t)b * CB + c + 1) * HH + y) * WW + x];
            lds_t[x * 17 + cpair] = pack_bf16(v0, v1);
            float s0 = v0, s1 = v1;
            #pragma unroll
            for (int off = 32; off; off >>= 1) {
                s0 += __shfl_down(s0, off, 64);
                s1 += __shfl_down(s1, off, 64);
            }
            if (lane == 0) {
                int cc = (ph >> 1) * 64 + c;
                poolacc[w][cc] = s0;
                poolacc[w][cc + 1] = s1;
            }
        }
        __syncthreads();
        {
            int p = t >> 1, h = t & 1;
            unsigned int vv[8];
            #pragma unroll
            for (int j = 0; j < 8; ++j) vv[j] = lds_t[p * 17 + h * 8 + j];
            unsigned int* dst = (ph >> 1) ? dstD : dstR;
            unsigned int* dp = dst + (p + 1) * 32 + (chbase >> 1) + h * 8;
            uint4 q0 = {vv[0], vv[1], vv[2], vv[3]};
            uint4 q1 = {vv[4], vv[5], vv[6], vv[7]};
            *(uint4*)dp = q0;
            *(uint4*)(dp + 4) = q1;
        }
        __syncthreads();
    }
    if (t < 128) {
        int w0 = 2 * ((t >> 1) & 1);
        part[((size_t)b * 128 + y) * 128 + t] = poolacc[w0][t] + poolacc[w0 + 1][t];
    }
}

__global__ __launch_bounds__(256) void k_pool2(const float* __restrict__ part,
                                               float* __restrict__ ws) {
    int b = blockIdx.x, t = threadIdx.x, cc = t & 127, q = t >> 7;
    float s = 0.f;
    for (int y = q * 64; y < q * 64 + 64; ++y)
        s += part[((size_t)b * 128 + y) * 128 + cc];
    __shared__ float red[2][128];
    red[q][cc] = s;
    __syncthreads();
    if (t < 128)
        ws[WS_POOLED + b * 128 + t] = (red[0][t] + red[1][t]) * (1.f / 16384.f);
}

__global__ void k_hid(const float* __restrict__ w1, const float* __restrict__ b1,
                      float* __restrict__ ws) {
    __shared__ float p[128];
    int b = blockIdx.x, j = threadIdx.x;
    p[j] = ws[WS_POOLED + b * 128 + j];
    __syncthreads();
    if (j < CB) {
        float s = b1[j];
        const float* wr = w1 + j * 128;
        #pragma unroll 8
        for (int i = 0; i < 128; ++i) s += p[i] * wr[i];
        ws[WS_HID + b * CB + j] = fmaxf(s, 0.f);
    }
}

__global__ __launch_bounds__(256) void k_kern(const float* __restrict__ w2, const float* __restrict__ b2,
                                              float* __restrict__ ws) {
    __shared__ float h[CB];
    int b = blockIdx.x, t = threadIdx.x;
    if (t < CB) h[t] = ws[WS_HID + b * CB + t];
    __syncthreads();
    float local = 0.f;
    #pragma unroll
    for (int r9 = 0; r9 < 9; ++r9) {
        int r = t * 9 + r9;
        float s = b2[r];
        const float* wr = w2 + r * CB;
        #pragma unroll 8
        for (int m = 0; m < CB; ++m) s += h[m] * wr[m];
        ws[WS_KERN + b * 2304 + r] = s;
        local += s * s;
    }
    #pragma unroll
    for (int off = 32; off; off >>= 1) local += __shfl_down(local, off, 64);
    if ((t & 63) == 0) ws[WS_SSQ + b * KK + (t >> 6)] = local;
}

__global__ __launch_bounds__(256) void k_wk(float* __restrict__ ws) {
    __shared__ float attn[KK];
    int b = blockIdx.x, t = threadIdx.x;
    if (t == 0) {
        float n[KK], m = -1e30f;
        #pragma unroll
        for (int k = 0; k < KK; ++k) { n[k] = sqrtf(ws[WS_SSQ + b * KK + k]); m = fmaxf(m, n[k]); }
        float e[KK], den = 0.f;
        #pragma unroll
        for (int k = 0; k < KK; ++k) { e[k] = expf(n[k] - m); den += e[k]; }
        float inv = 1.f / den;
        #pragma unroll
        for (int k = 0; k < KK; ++k) attn[k] = e[k] * inv;
    }
    __syncthreads();
    const float* kb = ws + WS_KERN + b * 2304;
    float a0 = attn[0], a1 = attn[1], a2 = attn[2], a3 = attn[3];
    for (int idx = t; idx < 576; idx += 256) {
        float s = a0 * kb[idx] + a1 * kb[576 + idx] + a2 * kb[1152 + idx] + a3 * kb[1728 + idx];
        ws[WS_WK + b * 576 + idx] = s;
    }
}

__global__ __launch_bounds__(256) void k_effw(const float* __restrict__ fu_w, float* __restrict__ ws) {
    int o = blockIdx.x, t = threadIdx.x;
    __shared__ float fw[CB];
    float fi = ws[WS_FUINV + o];
    if (t < CB) {
        fw[t] = fu_w[o * 128 + t] * fi;
        ws[WS_FUW2 + o * CB + t] = fu_w[o * 128 + CB + t] * fi;
    }
    __syncthreads();
    for (int idx = t; idx < 576; idx += 256) {
        float s = 0.f;
        #pragma unroll 8
        for (int c = 0; c < CB; ++c) s += fw[c] * ws[WS_WK + c * 576 + idx];
        ws[WS_EFFW + o * 576 + idx] = s;
    }
}

__global__ void k_prepw(const float* __restrict__ fd_w, float* __restrict__ ws) {
    int e = blockIdx.x * 256 + threadIdx.x;
    unsigned short* wt3 = (unsigned short*)((char*)ws + WT3_BYTE);
    unsigned short* wfd = (unsigned short*)((char*)ws + WFD_BYTE);
    unsigned short* w1o = (unsigned short*)((char*)ws + W1_BYTE);
    if (e < 36864) {
        int tap = e >> 12, rem = e & 4095, o = rem >> 6, ci = rem & 63;
        __hip_bfloat16 h = __float2bfloat16(ws[WS_EFFW + o * 576 + ci * 9 + tap]);
        wt3[e] = *(unsigned short*)&h;
    } else if (e < 73728) {
        int e2 = e - 36864;
        int tap = e2 >> 12, rem = e2 & 4095, o = rem >> 6, ci = rem & 63;
        __hip_bfloat16 h = __float2bfloat16(fd_w[(o * 64 + ci) * 9 + tap] * ws[WS_FDINV + o]);
        wfd[e2] = *(unsigned short*)&h;
    } else if (e < 77824) {
        int e3 = e - 73728;
        __hip_bfloat16 h = __float2bfloat16(ws[WS_FUW2 + e3]);
        w1o[e3] = *(unsigned short*)&h;
    }
}

// ---------------- fused conv kernel (weight-stationary) ----------------
// Tile 32x8 px. Input LDS: [10 rows][34 x][8 chunks of 8 bf16] = 43520 B,
// linear dest, XOR swizzle (cs ^ (x&7)) on global source + ds_read side.
// Wave w owns output channels [16w, 16w+16) for ALL 256 tile pixels;
// the 18 weight A-fragments/conv live in registers for the whole conv.

__device__ __forceinline__ void gload_lds16(const void* g, void* l) {
    __builtin_amdgcn_global_load_lds((const __attribute__((address_space(1))) unsigned int*)g,
                                     (__attribute__((address_space(3))) unsigned int*)l, 16, 0, 0);
}

__device__ __forceinline__ void stage_async(const unsigned short* __restrict__ T, int b,
                                            int y0p, int x0p, int t, char* tile) {
    const char* base = (const char*)(T + (((size_t)b * 130 + y0p) * 130 + x0p) * 64);
    #pragma unroll
    for (int it = 0; it < 10; ++it) {
        int n = it * 256 + t;
        int row = n / 272, rem = n - row * 272;
        int xx = rem >> 3, cs = rem & 7;
        gload_lds16(base + (size_t)row * 16640 + xx * 128 + ((cs ^ (xx & 7)) << 4),
                    tile + n * 16);
    }
    if (t < 160) {
        int n = 2560 + t;
        int row = n / 272, rem = n - row * 272;
        int xx = rem >> 3, cs = rem & 7;
        gload_lds16(base + (size_t)row * 16640 + xx * 128 + ((cs ^ (xx & 7)) << 4),
                    tile + n * 16);
    }
}

// load the 18 A-fragments for one conv phase (wave's 16 out-channels)
__device__ __forceinline__ void load_wfrag(short8 (&wa)[18], const unsigned short* __restrict__ W,
                                           int w, int lx, int lq) {
    #pragma unroll
    for (int tap = 0; tap < 9; ++tap)
        #pragma unroll
        for (int cb = 0; cb < 2; ++cb)
            wa[tap * 2 + cb] = *(const short8*)(W + (tap * 64 + w * 16 + lx) * 64 + cb * 32 + lq * 8);
}

// conv3x3 with register-resident weights; B-frags via base+imm ds_reads.
// byte = ((nt>>1)+di)*4352 + ((nt&1)*16+lx+dj)*128 + (((cb*4+lq)^((lx+dj)&7))<<4)
__device__ __forceinline__ void conv3x3w(f32x4 (&acc)[16], const short8 (&wa)[18],
                                         const char* tile, int lx, int lq) {
    #pragma unroll
    for (int dj = 0; dj < 3; ++dj) {
        #pragma unroll
        for (int cb = 0; cb < 2; ++cb) {
            const char* base = tile + (lx + dj) * 128 + (((cb * 4 + lq) ^ ((lx + dj) & 7)) << 4);
            #pragma unroll
            for (int di = 0; di < 3; ++di) {
                short8 aw = wa[(di * 3 + dj) * 2 + cb];
                __builtin_amdgcn_s_setprio(1);
                #pragma unroll
                for (int nt = 0; nt < 16; ++nt) {
                    short8 bf = *(const short8*)(base + (nt >> 1) * 4352 + di * 4352 + (nt & 1) * 2048);
                    acc[nt] = __builtin_amdgcn_mfma_f32_16x16x32_bf16(aw, bf, acc[nt], 0, 0, 0);
                }
                __builtin_amdgcn_s_setprio(0);
            }
        }
    }
}

__global__ __launch_bounds__(256, 3) void k_fused(const unsigned short* __restrict__ rgbT,
                                                  const unsigned short* __restrict__ depthT,
                                                  const float* __restrict__ ws,
                                                  float* __restrict__ out) {
    __shared__ __align__(16) char tile[43520];
    int b = blockIdx.z;
    int x0 = blockIdx.x * 32, y0 = blockIdx.y * 8;
    int t = threadIdx.x, lane = t & 63, w = t >> 6;
    int lx = lane & 15, lq = lane >> 4;

    const unsigned short* wfd = (const unsigned short*)((const char*)ws + WFD_BYTE);
    const unsigned short* wt3 = (const unsigned short*)((const char*)ws + WT3_BYTE);
    const unsigned short* w1o = (const unsigned short*)((const char*)ws + W1_BYTE);

    // ---- issue depth tile loads (async into LDS); weights load beneath ----
    stage_async(depthT, b, y0, x0, t, tile);

    short8 wa[18];
    load_wfrag(wa, wfd, w, lx, lq);

    f32x4 facc[16];
    {
        f32x4 bi;
        #pragma unroll
        for (int i = 0; i < 4; ++i) bi[i] = ws[WS_FDBETA + w * 16 + lq * 4 + i];
        #pragma unroll
        for (int nt = 0; nt < 16; ++nt) facc[nt] = bi;
    }
    __syncthreads();   // depth tile resident

    // ---- freq = relu(BN(conv3x3(depth))), wave's 16 channels x 256 px ----
    conv3x3w(facc, wa, tile, lx, lq);
    __syncthreads();   // depth-tile reads done; reuse tile[0..32768) as freq_lds

    // ---- write freq to LDS: [pixel][ch] bf16, 16B-slot XOR by (p&7) ----
    {
        unsigned int* fl = (unsigned int*)tile;
        #pragma unroll
        for (int nt = 0; nt < 16; ++nt) {
            int p = nt * 16 + lx;
            unsigned int u0 = pack_bf16(fmaxf(facc[nt][0], 0.f), fmaxf(facc[nt][1], 0.f));
            unsigned int u1 = pack_bf16(fmaxf(facc[nt][2], 0.f), fmaxf(facc[nt][3], 0.f));
            int slot = ((w * 2) + (lq >> 1)) ^ (p & 7);
            int dw = p * 32 + slot * 4 + (lq & 1) * 2;
            fl[dw] = u0;
            fl[dw + 1] = u1;
        }
    }
    __syncthreads();   // freq_lds visible

    // ---- acc init + 1x1 over freq (A = w1 frags in regs, B from freq_lds) ----
    f32x4 acc[16];
    {
        f32x4 bi;
        #pragma unroll
        for (int i = 0; i < 4; ++i) bi[i] = ws[WS_FUBETA + w * 16 + lq * 4 + i];
        #pragma unroll
        for (int nt = 0; nt < 16; ++nt) acc[nt] = bi;
    }
    #pragma unroll
    for (int cb = 0; cb < 2; ++cb) {
        short8 aw = *(const short8*)(w1o + (w * 16 + lx) * 64 + cb * 32 + lq * 8);
        __builtin_amdgcn_s_setprio(1);
        #pragma unroll
        for (int nt = 0; nt < 16; ++nt) {
            int p = nt * 16 + lx;
            int slot = (cb * 4 + lq) ^ (p & 7);
            short8 bf = *(const short8*)(tile + p * 128 + slot * 16);
            acc[nt] = __builtin_amdgcn_mfma_f32_16x16x32_bf16(aw, bf, acc[nt], 0, 0, 0);
        }
        __builtin_amdgcn_s_setprio(0);
    }
    __syncthreads();   // freq_lds reads done

    // ---- issue rgb tile loads; wt3 frags load beneath ----
    stage_async(rgbT, b, y0, x0, t, tile);
    load_wfrag(wa, wt3, w, lx, lq);
    __syncthreads();   // rgb tile resident

    // ---- dynamic conv over rgb ----
    conv3x3w(acc, wa, tile, lx, lq);
    __syncthreads();   // tile reads done; reuse as transpose slab

    // ---- epilogue: per-wave LDS transpose -> full-128B-line stores ----
    float* slab = (float*)tile + w * 528;      // 16 ch x 33 floats
    int og = lane >> 5, xi = lane & 31;
    #pragma unroll
    for (int y = 0; y < 8; ++y) {
        #pragma unroll
        for (int xh = 0; xh < 2; ++xh) {
            int nt = y * 2 + xh;
            #pragma unroll
            for (int i = 0; i < 4; ++i)
                slab[(lq * 4 + i) * 33 + xh * 16 + lx] = fmaxf(acc[nt][i], 0.f);
        }
        size_t rowbase = (((size_t)(b * CB + w * 16)) * HH + (y0 + y)) * WW + x0;
        #pragma unroll
        for (int k = 0; k < 8; ++k) {
            int o = k * 2 + og;
            out[rowbase + (size_t)o * HWSZ + xi] = slab[o * 33 + xi];
        }
    }
}

// ---------------- launch ----------------

extern "C" void kernel_launch(void* const* d_in, const int* in_sizes, int n_in,
                              void* d_out, int out_size, void* d_ws, size_t ws_size,
                              hipStream_t stream) {
    const float* rgb      = (const float*)d_in[0];
    const float* depth    = (const float*)d_in[1];
    const float* w1       = (const float*)d_in[2];
    const float* b1       = (const float*)d_in[3];
    const float* w2       = (const float*)d_in[4];
    const float* b2       = (const float*)d_in[5];
    const float* fd_w     = (const float*)d_in[6];
    const float* fd_b     = (const float*)d_in[7];
    const float* fd_scale = (const float*)d_in[8];
    const float* fd_bias  = (const float*)d_in[9];
    const float* fd_mean  = (const float*)d_in[10];
    const float* fd_var   = (const float*)d_in[11];
    const float* fu_w     = (const float*)d_in[12];
    const float* fu_b     = (const float*)d_in[13];
    const float* fu_scale = (const float*)d_in[14];
    const float* fu_bias  = (const float*)d_in[15];
    const float* fu_mean  = (const float*)d_in[16];
    const float* fu_var   = (const float*)d_in[17];

    float* ws = (float*)d_ws;
    float* part = (float*)((char*)d_ws + WS_PART_BYTE);
    unsigned int* depthT = (unsigned int*)((char*)d_ws + WS_DEPTHT_BYTE);
    unsigned int* rgbT   = (unsigned int*)((char*)d_ws + WS_RGBT_BYTE);
    float* out = (float*)d_out;

    k_consts<<<1, 64, 0, stream>>>(fd_scale, fd_bias, fd_mean, fd_var, fd_b,
                                   fu_scale, fu_bias, fu_mean, fu_var, fu_b, ws);
    k_nhwc<<<dim3(130, 64), 256, 0, stream>>>(rgb, depth, rgbT, depthT, part);
    k_pool2<<<CB, 256, 0, stream>>>(part, ws);
    k_hid<<<CB, 128, 0, stream>>>(w1, b1, ws);
    k_kern<<<CB, 256, 0, stream>>>(w2, b2, ws);
    k_wk<<<CB, 256, 0, stream>>>(ws);
    k_effw<<<CB, 256, 0, stream>>>(fu_w, ws);
    k_prepw<<<304, 256, 0, stream>>>(fd_w, ws);

    dim3 grid(WW / 32, HH / 8, CB);
    k_fused<<<grid, 256, 0, stream>>>((const unsigned short*)rgbT,
                                      (const unsigned short*)depthT, ws, out);
}